// Round 14
// baseline (93.179 us; speedup 1.0000x reference)
//
#include <hip/hip_runtime.h>
#include <hip/hip_bf16.h>
#include <math.h>

#define TT 577          // real tokens per n
#define TP 640          // padded tokens per n
#define CCH 768         // channels
#define KR 64           // regions
#define NB 64           // batch
#define SLAB 32         // tokens per k_logits block
#define NSLAB 19        // slabs per n (19*32 = 608 >= 577)

typedef __attribute__((ext_vector_type(8))) short bf16x8;
typedef __attribute__((ext_vector_type(8))) unsigned short ushort8;
typedef __attribute__((ext_vector_type(4))) float f32x4;

static constexpr float EPSF = 1e-12f;

static __device__ inline unsigned short f2bf(float f) {
    return __bfloat16_as_ushort(__float2bfloat16(f));
}
static __device__ inline float bf2f(unsigned short b) {
    union { unsigned int u; float f; } v; v.u = ((unsigned int)b) << 16;
    return v.f;
}

// ---------------------------------------------------------------------------
// Kernel 0: prep. (a) conv_w fp32 -> bf16 ws_w[64][768]; (b) zero ws_a row
// tails t in [608,640). Grid 24 x 256.
// ---------------------------------------------------------------------------
__global__ __launch_bounds__(256) void k_prep(
    const float* __restrict__ conv_w,
    unsigned short* __restrict__ ws_w,
    unsigned short* __restrict__ ws_a)
{
    const int g = blockIdx.x * 256 + threadIdx.x;   // [0, 6144)
    if (g < 6144) {
        const float* s = conv_w + (size_t)g * 8;
        float4 v0 = *reinterpret_cast<const float4*>(s);
        float4 v1 = *reinterpret_cast<const float4*>(s + 4);
        ushort8 o;
        o[0]=f2bf(v0.x); o[1]=f2bf(v0.y); o[2]=f2bf(v0.z); o[3]=f2bf(v0.w);
        o[4]=f2bf(v1.x); o[5]=f2bf(v1.y); o[6]=f2bf(v1.z); o[7]=f2bf(v1.w);
        *reinterpret_cast<ushort8*>(ws_w + (size_t)g * 8) = o;
    }
    if (g < 4096) {
        unsigned short* d = ws_a + (size_t)g * TP + 608;
        ushort8 z = {0,0,0,0,0,0,0,0};
        #pragma unroll
        for (int i = 0; i < 4; ++i)
            *reinterpret_cast<ushort8*>(d + i * 8) = z;
    }
}

// ---------------------------------------------------------------------------
// Kernel 1 v8 (single-stream slab): GEMM1 + norm + softmax + a' + asum.
// Grid: 1216 blocks (64 n x 19 slabs of 32 tokens), 256 thr = 4 waves.
// Phase A: ONE contiguous 96-KB grids read per block (32 full rows),
//          fp32->bf16 into LDS Xs. This is the m13-copy access shape:
//          few long sequential streams per CU -> HW prefetch works.
// Phase B: K-loop entirely LDS-fed. Waves split K in halves
//          (w={0,1}: c 0..63 of each 128-chunk; w={2,3}: c 64..127),
//          partial logits reduced via LDS, then proven softmax path.
// 2 blocks/CU (67.8 KB LDS): one block stages while the other computes.
// ---------------------------------------------------------------------------
__global__ __launch_bounds__(256, 2) void k_logits(
    const float* __restrict__ grids,
    const unsigned short* __restrict__ ws_w,
    const float* __restrict__ conv_b,
    unsigned short* __restrict__ ws_a,
    float* __restrict__ ws_asum)
{
    __shared__ __align__(16) unsigned short Xs[SLAB * 776];  // 49,664 B
    __shared__ __align__(16) unsigned short Wl[KR * 136];    // 17,408 B
    __shared__ float ssl[2][2][16];                          // [h][p][tok]
    __shared__ float asum_lds[2][64];

    const int tid  = threadIdx.x;
    const int lane = tid & 63;
    const int w    = tid >> 6;
    const int p    = w & 1;          // token-pair (t-tile)
    const int h    = w >> 1;         // K-half within chunk
    // XCD-chunked bijective swizzle: 1216 = 8 x 152
    const int b    = (blockIdx.x & 7) * 152 + (blockIdx.x >> 3);
    const int n    = b / NSLAB;
    const int sb   = b - n * NSLAB;
    const int t0   = sb << 5;

    const int lr = lane & 15;
    const int lg = lane >> 4;

    ushort8 wa[4];
    auto wload = [&](int ch) {
        const int c0 = ch << 7;
        #pragma unroll
        for (int it = 0; it < 4; ++it) {
            const int kr = it * 16 + (tid >> 4);
            wa[it] = *reinterpret_cast<const ushort8*>(
                ws_w + (size_t)kr * CCH + c0 + ((tid & 15) << 3));
        }
    };
    auto wstore = [&]() {
        #pragma unroll
        for (int it = 0; it < 4; ++it) {
            const int kr = it * 16 + (tid >> 4);
            *reinterpret_cast<ushort8*>(&Wl[kr * 136 + ((tid & 15) << 3)]) = wa[it];
        }
    };

    // ---- Phase A: stage slab (one contiguous 96-KB region) ----
    wload(0);                                     // W chunk 0 in flight too
    {
        const int lim = TT - t0;                  // valid tokens in slab
        const float* gsl = grids + ((size_t)n * TT + t0) * CCH;
        #pragma unroll
        for (int it = 0; it < 24; ++it) {
            const int f  = (it << 8) + tid;       // [0, 6144) float4 units
            const int t  = f / 192;
            const int c4 = f - t * 192;
            float4 v = (t < lim)
                ? *reinterpret_cast<const float4*>(gsl + (size_t)t * CCH + (c4 << 2))
                : make_float4(0.f, 0.f, 0.f, 0.f);
            unsigned short o4[4] = { f2bf(v.x), f2bf(v.y), f2bf(v.z), f2bf(v.w) };
            *reinterpret_cast<uint2*>(&Xs[t * 776 + (c4 << 2)]) =
                *reinterpret_cast<const uint2*>(o4);
        }
    }
    wstore();
    __syncthreads();

    // ---- Phase B: K loop, all operands from LDS ----
    f32x4 acc[4] = {};
    float ss = 0.f;
    const int co = h << 6;                        // wave's c-offset in chunk

    for (int ch = 0; ch < 6; ++ch) {
        if (ch < 5) wload(ch + 1);                // T14: issue early (L2)
        const int cb = ch << 7;
        #pragma unroll
        for (int s2 = 0; s2 < 2; ++s2) {
            const int cs = co + (s2 << 5) + (lg << 3);     // within chunk
            bf16x8 af = *reinterpret_cast<const bf16x8*>(
                &Xs[(p * 16 + lr) * 776 + cb + cs]);
            #pragma unroll
            for (int j = 0; j < 8; ++j) {
                const float v = bf2f(((unsigned short*)&af)[j]);
                ss = fmaf(v, v, ss);
            }
            bf16x8 b0 = *reinterpret_cast<const bf16x8*>(&Wl[ lr        * 136 + cs]);
            bf16x8 b1 = *reinterpret_cast<const bf16x8*>(&Wl[(16 + lr) * 136 + cs]);
            bf16x8 b2 = *reinterpret_cast<const bf16x8*>(&Wl[(32 + lr) * 136 + cs]);
            bf16x8 b3 = *reinterpret_cast<const bf16x8*>(&Wl[(48 + lr) * 136 + cs]);
            acc[0] = __builtin_amdgcn_mfma_f32_16x16x32_bf16(af, b0, acc[0], 0, 0, 0);
            acc[1] = __builtin_amdgcn_mfma_f32_16x16x32_bf16(af, b1, acc[1], 0, 0, 0);
            acc[2] = __builtin_amdgcn_mfma_f32_16x16x32_bf16(af, b2, acc[2], 0, 0, 0);
            acc[3] = __builtin_amdgcn_mfma_f32_16x16x32_bf16(af, b3, acc[3], 0, 0, 0);
        }
        __syncthreads();                          // done reading Wl chunk
        if (ch < 5) { wstore(); __syncthreads(); }
    }

    // ---- half-K token sumsq -> LDS ----
    ss += __shfl_xor(ss, 16);
    ss += __shfl_xor(ss, 32);
    if (lane < 16) ssl[h][p][lane] = ss;

    // ---- partial logits -> LDS (plog aliases Wl: 16 KB <= 17.4 KB) ----
    float* plog = reinterpret_cast<float*>(&Wl[0]);
    #pragma unroll
    for (int rt = 0; rt < 4; ++rt) {
        #pragma unroll
        for (int reg = 0; reg < 4; ++reg)
            plog[(((h * 2 + p) * 16) + (lg * 4 + reg)) * 64 + rt * 16 + lr] =
                acc[rt][reg];
    }
    __syncthreads();

    // ---- waves 0,1: combine halves, softmax, asum, a' ----
    if (w < 2) {
        const int p2  = w;
        const int t0w = t0 + (p2 << 4);

        const float ssf = ssl[0][p2][lr] + ssl[1][p2][lr];
        const float nrm = sqrtf(ssf);
        const float inv = 1.0f / fmaxf(nrm, EPSF);

        float b_[4];
        #pragma unroll
        for (int rt = 0; rt < 4; ++rt) b_[rt] = conv_b[rt * 16 + lr];

        float invT[4];
        #pragma unroll
        for (int reg = 0; reg < 4; ++reg) invT[reg] = __shfl(inv, (lg << 2) + reg);

        const float* pl0 = &plog[(p2 * 16) * 64];
        const float* pl1 = &plog[((2 + p2) * 16) * 64];

        float lgt[4][4], mx[4];
        #pragma unroll
        for (int reg = 0; reg < 4; ++reg) {
            const int tok = (lg << 2) + reg;
            float m = -1e30f;
            #pragma unroll
            for (int rt = 0; rt < 4; ++rt) {
                const int k = rt * 16 + lr;
                const float raw = pl0[tok * 64 + k] + pl1[tok * 64 + k];
                lgt[rt][reg] = fmaf(raw, invT[reg], b_[rt]);
                m = fmaxf(m, lgt[rt][reg]);
            }
            mx[reg] = m;
        }
        #pragma unroll
        for (int msk = 1; msk < 16; msk <<= 1) {
            #pragma unroll
            for (int reg = 0; reg < 4; ++reg)
                mx[reg] = fmaxf(mx[reg], __shfl_xor(mx[reg], msk));
        }
        float ex[4][4], sm[4] = {0.f, 0.f, 0.f, 0.f};
        #pragma unroll
        for (int rt = 0; rt < 4; ++rt) {
            #pragma unroll
            for (int reg = 0; reg < 4; ++reg) {
                ex[rt][reg] = __expf(lgt[rt][reg] - mx[reg]);
                sm[reg] += ex[rt][reg];
            }
        }
        #pragma unroll
        for (int msk = 1; msk < 16; msk <<= 1) {
            #pragma unroll
            for (int reg = 0; reg < 4; ++reg)
                sm[reg] += __shfl_xor(sm[reg], msk);
        }

        float rsm[4];
        #pragma unroll
        for (int reg = 0; reg < 4; ++reg) {
            const bool vt = (t0w + (lg << 2) + reg) < TT;
            rsm[reg] = vt ? (1.0f / sm[reg]) : 0.f;
        }

        float pa[4];
        #pragma unroll
        for (int rt = 0; rt < 4; ++rt) {
            pa[rt] = ex[rt][0]*rsm[0] + ex[rt][1]*rsm[1]
                   + ex[rt][2]*rsm[2] + ex[rt][3]*rsm[3];
            pa[rt] += __shfl_xor(pa[rt], 16);
            pa[rt] += __shfl_xor(pa[rt], 32);
        }
        if (lane < 16) {
            #pragma unroll
            for (int rt = 0; rt < 4; ++rt)
                asum_lds[p2][rt * 16 + lane] = pa[rt];
        }

        // a' transpose into Xs (free after K loop)
        unsigned short* Ab = &Xs[0] + (size_t)p2 * KR * 24;
        #pragma unroll
        for (int reg = 0; reg < 4; ++reg) {
            const int trow = (lg << 2) + reg;
            const float scale = invT[reg] * rsm[reg];
            #pragma unroll
            for (int rt = 0; rt < 4; ++rt)
                Ab[(rt * 16 + lr) * 24 + trow] = f2bf(ex[rt][reg] * scale);
        }
    }
    __syncthreads();

    if (tid < 64)
        ws_asum[((size_t)n * NSLAB + sb) * 64 + tid] =
            asum_lds[0][tid] + asum_lds[1][tid];

    if (w < 2) {
        const unsigned short* Ab = &Xs[0] + (size_t)w * KR * 24;
        ushort8 r0 = *reinterpret_cast<const ushort8*>(&Ab[lane * 24]);
        ushort8 r1 = *reinterpret_cast<const ushort8*>(&Ab[lane * 24 + 8]);
        unsigned short* dst = ws_a + ((size_t)n * KR + lane) * TP + t0 + (w << 4);
        *reinterpret_cast<ushort8*>(dst)     = r0;
        *reinterpret_cast<ushort8*>(dst + 8) = r1;
    }
}

// ---------------------------------------------------------------------------
// Kernel 2: GEMM2 (VLAD), R13 structure (XCD swizzle, fp32 B gathers).
// ---------------------------------------------------------------------------
#define LOADA(d0,d1,d2,d3,t0_)                                                   \
    d0 = *reinterpret_cast<const bf16x8*>(abase +           (size_t)(t0_));      \
    d1 = *reinterpret_cast<const bf16x8*>(abase + 16*TP +   (size_t)(t0_));      \
    d2 = *reinterpret_cast<const bf16x8*>(abase + 32*TP +   (size_t)(t0_));      \
    d3 = *reinterpret_cast<const bf16x8*>(abase + 48*TP +   (size_t)(t0_));

#define LOADB(d,t0_) do {                                                        \
    const int tb2_ = (t0_) + (lg << 3);                                          \
    if ((t0_) + 32 <= TT) {                                                      \
        _Pragma("unroll")                                                        \
        for (int j_ = 0; j_ < 8; ++j_)                                           \
            ((unsigned short*)&(d))[j_] = f2bf(gb[(size_t)(tb2_ + j_) * CCH]);   \
    } else {                                                                     \
        _Pragma("unroll")                                                        \
        for (int j_ = 0; j_ < 8; ++j_) {                                         \
            float v_ = (tb2_ + j_ < TT) ? gb[(size_t)(tb2_ + j_) * CCH] : 0.f;   \
            ((unsigned short*)&(d))[j_] = f2bf(v_);                              \
        }                                                                        \
    } } while (0)

__global__ __launch_bounds__(256, 4) void k_vlad(
    const float* __restrict__ grids,
    const unsigned short* __restrict__ ws_a,
    const float* __restrict__ ws_asum,
    const float* __restrict__ centroids,
    float* __restrict__ out)
{
    __shared__ float asum_s[64];

    const int tid  = threadIdx.x;
    const int lane = tid & 63;
    const int w    = tid >> 6;
    const int b    = (blockIdx.x & 7) * 96 + (blockIdx.x >> 3);
    const int n    = b / 12;
    const int c0   = (b - n * 12) << 6;
    const int lr   = lane & 15;
    const int lg   = lane >> 4;

    if (tid < 64) {
        float s = 0.f;
        #pragma unroll
        for (int bb = 0; bb < NSLAB; ++bb)
            s += ws_asum[((size_t)n * NSLAB + bb) * 64 + tid];
        asum_s[tid] = s;
    }
    __syncthreads();

    const int c = c0 + (w << 4) + lr;
    const unsigned short* abase = ws_a + ((size_t)n * KR + lr) * TP + (lg << 3);
    const float* gb = grids + (size_t)n * TT * CCH + c;

    f32x4 acc0 = {}, acc1 = {}, acc2 = {}, acc3 = {};
    bf16x8 a0, a1, a2, a3, b0;
    bf16x8 p0, p1, p2, p3, q0;

    LOADA(a0, a1, a2, a3, 0)
    LOADB(b0, 0);

    int t0 = 0;
    while (true) {
        int tn = t0 + 32;
        if (tn < TT) { LOADA(p0, p1, p2, p3, tn) LOADB(q0, tn); }
        acc0 = __builtin_amdgcn_mfma_f32_16x16x32_bf16(a0, b0, acc0, 0, 0, 0);
        acc1 = __builtin_amdgcn_mfma_f32_16x16x32_bf16(a1, b0, acc1, 0, 0, 0);
        acc2 = __builtin_amdgcn_mfma_f32_16x16x32_bf16(a2, b0, acc2, 0, 0, 0);
        acc3 = __builtin_amdgcn_mfma_f32_16x16x32_bf16(a3, b0, acc3, 0, 0, 0);
        t0 = tn;
        if (t0 >= TT) break;

        tn = t0 + 32;
        if (tn < TT) { LOADA(a0, a1, a2, a3, tn) LOADB(b0, tn); }
        acc0 = __builtin_amdgcn_mfma_f32_16x16x32_bf16(p0, q0, acc0, 0, 0, 0);
        acc1 = __builtin_amdgcn_mfma_f32_16x16x32_bf16(p1, q0, acc1, 0, 0, 0);
        acc2 = __builtin_amdgcn_mfma_f32_16x16x32_bf16(p2, q0, acc2, 0, 0, 0);
        acc3 = __builtin_amdgcn_mfma_f32_16x16x32_bf16(p3, q0, acc3, 0, 0, 0);
        t0 = tn;
        if (t0 >= TT) break;
    }

    #pragma unroll
    for (int reg = 0; reg < 4; ++reg) {
        {
            const int kr = 0*16 + (lg << 2) + reg;
            out[((size_t)n * KR + kr) * CCH + c] =
                acc0[reg] - asum_s[kr] * centroids[(size_t)kr * CCH + c];
        }
        {
            const int kr = 1*16 + (lg << 2) + reg;
            out[((size_t)n * KR + kr) * CCH + c] =
                acc1[reg] - asum_s[kr] * centroids[(size_t)kr * CCH + c];
        }
        {
            const int kr = 2*16 + (lg << 2) + reg;
            out[((size_t)n * KR + kr) * CCH + c] =
                acc2[reg] - asum_s[kr] * centroids[(size_t)kr * CCH + c];
        }
        {
            const int kr = 3*16 + (lg << 2) + reg;
            out[((size_t)n * KR + kr) * CCH + c] =
                acc3[reg] - asum_s[kr] * centroids[(size_t)kr * CCH + c];
        }
    }
}

// ---------------------------------------------------------------------------
// Kernel 3: 4 rows per 256-thr block; global L2 norm of 64 unit rows = 8.
// ---------------------------------------------------------------------------
__global__ __launch_bounds__(256) void kc_norm_kernel(float* __restrict__ out)
{
    const int tid = threadIdx.x;
    const int sub = tid >> 6;
    const int l   = tid & 63;
    float4* p = reinterpret_cast<float4*>(out) + ((size_t)blockIdx.x * 4 + sub) * 192;
    float4 v0 = p[l];
    float4 v1 = p[l + 64];
    float4 v2 = p[l + 128];
    float ss = v0.x*v0.x + v0.y*v0.y + v0.z*v0.z + v0.w*v0.w
             + v1.x*v1.x + v1.y*v1.y + v1.z*v1.z + v1.w*v1.w
             + v2.x*v2.x + v2.y*v2.y + v2.z*v2.z + v2.w*v2.w;
    #pragma unroll
    for (int m = 1; m < 64; m <<= 1) ss += __shfl_xor(ss, m);
    const float sc = 0.125f / fmaxf(sqrtf(ss), EPSF);
    v0.x*=sc; v0.y*=sc; v0.z*=sc; v0.w*=sc;
    v1.x*=sc; v1.y*=sc; v1.z*=sc; v1.w*=sc;
    v2.x*=sc; v2.y*=sc; v2.z*=sc; v2.w*=sc;
    p[l] = v0;
    p[l + 64] = v1;
    p[l + 128] = v2;
}

extern "C" void kernel_launch(void* const* d_in, const int* in_sizes, int n_in,
                              void* d_out, int out_size, void* d_ws, size_t ws_size,
                              hipStream_t stream)
{
    const float* grids     = (const float*)d_in[0];
    const float* conv_w    = (const float*)d_in[1];
    const float* conv_b    = (const float*)d_in[2];
    const float* centroids = (const float*)d_in[3];
    float* out = (float*)d_out;

    // ws layout (bytes):
    //   ws_a    [0,         5,242,880)   64*64*640 bf16
    //   ws_asum [5,242,880, 5,554,176)   1216*64 f32 (311,296 B)
    //   ws_w    [5,554,176, 5,652,480)   64*768 bf16 (98,304 B)
    unsigned short* ws_a    = (unsigned short*)d_ws;
    float*          ws_asum = (float*)((char*)d_ws + 5242880);
    unsigned short* ws_w    = (unsigned short*)((char*)d_ws + 5554176);

    hipLaunchKernelGGL(k_prep, dim3(24), dim3(256), 0, stream,
                       conv_w, ws_w, ws_a);
    hipLaunchKernelGGL(k_logits, dim3(NB * NSLAB), dim3(256), 0, stream,
                       grids, ws_w, conv_b, ws_a, ws_asum);
    hipLaunchKernelGGL(k_vlad, dim3(NB * 12), dim3(256), 0, stream,
                       grids, ws_a, ws_asum, centroids, out);
    hipLaunchKernelGGL(kc_norm_kernel, dim3(NB * KR / 4), dim3(256), 0, stream, out);
}

// Round 15
// 89.168 us; speedup vs baseline: 1.0450x; 1.0450x over previous
//
#include <hip/hip_runtime.h>
#include <hip/hip_bf16.h>
#include <math.h>

#define TT 577          // real tokens per n
#define TP 640          // padded tokens per n
#define CCH 768         // channels
#define KR 64           // regions
#define NB 64           // batch

typedef __attribute__((ext_vector_type(8))) short bf16x8;
typedef __attribute__((ext_vector_type(8))) unsigned short ushort8;
typedef __attribute__((ext_vector_type(4))) float f32x4;

static constexpr float EPSF = 1e-12f;

static __device__ inline unsigned short f2bf(float f) {
    return __bfloat16_as_ushort(__float2bfloat16(f));
}
static __device__ inline float bf2f(unsigned short b) {
    union { unsigned int u; float f; } v; v.u = ((unsigned int)b) << 16;
    return v.f;
}

// ---------------------------------------------------------------------------
// Kernel W: pure m13-shape streaming convert-copy grids fp32 -> ws_g bf16.
// Grid-stride, ascending addresses across the whole GPU, no LDS, no deps
// beyond load->cvt->store: maximal MLP, DRAM-page-friendly miss stream.
// This is BOTH the fix (all later kernels read warm bf16) AND the decisive
// diagnostic (its counters = true achievable grids-touch bandwidth).
// ---------------------------------------------------------------------------
__global__ __launch_bounds__(256) void k_warm(
    const float* __restrict__ grids,
    unsigned short* __restrict__ ws_g)
{
    const size_t NF4 = (size_t)NB * TT * CCH / 4;    // 7,087,104 float4 units
    const size_t stride = (size_t)gridDim.x * 256;
    for (size_t i = (size_t)blockIdx.x * 256 + threadIdx.x; i < NF4; i += stride) {
        float4 v = reinterpret_cast<const float4*>(grids)[i];
        unsigned short o4[4] = { f2bf(v.x), f2bf(v.y), f2bf(v.z), f2bf(v.w) };
        *reinterpret_cast<uint2*>(ws_g + i * 4) = *reinterpret_cast<const uint2*>(o4);
    }
}

// ---------------------------------------------------------------------------
// Kernel 1 (R13 structure; A-side now bf16 b128 loads from warm ws_g):
// GEMM1 + norm + softmax + a' transpose + partial asum.
// Grid 640, XCD-chunked swizzle. W double-buffered in LDS (fp32->bf16).
// ---------------------------------------------------------------------------
__global__ __launch_bounds__(256, 3) void k_logits(
    const unsigned short* __restrict__ ws_g,
    const float* __restrict__ conv_w,
    const float* __restrict__ conv_b,
    unsigned short* __restrict__ ws_a,
    float* __restrict__ ws_asum)
{
    __shared__ __align__(16) unsigned short Wl[2][KR * 136];   // 2 x 17.4 KB

    const int tid  = threadIdx.x;
    const int lane = tid & 63;
    const int w    = tid >> 6;
    const int b    = (blockIdx.x & 7) * 80 + (blockIdx.x >> 3);
    const int n    = b / 10;
    const int tb   = (b - n * 10) << 6;
    const int t0w  = tb + (w << 4);

    const int lr = lane & 15;
    const int lg = lane >> 4;

    const int tokA = t0w + lr;
    const bool validA = (tokA < TT);
    const unsigned short* gsrc = ws_g + ((size_t)n * TT + tokA) * CCH + (lg << 3);

    float4 wreg[4][2];
    auto load_w = [&](int c0) {
        #pragma unroll
        for (int it = 0; it < 4; ++it) {
            int f = tid + (it << 8);
            int kr = f >> 4, c8 = (f & 15) << 3;
            const float* src = conv_w + (size_t)kr * CCH + c0 + c8;
            wreg[it][0] = *reinterpret_cast<const float4*>(src);
            wreg[it][1] = *reinterpret_cast<const float4*>(src + 4);
        }
    };
    auto store_w = [&](int buf) {
        #pragma unroll
        for (int it = 0; it < 4; ++it) {
            int f = tid + (it << 8);
            int kr = f >> 4, c8 = (f & 15) << 3;
            ushort8 o;
            o[0] = f2bf(wreg[it][0].x); o[1] = f2bf(wreg[it][0].y);
            o[2] = f2bf(wreg[it][0].z); o[3] = f2bf(wreg[it][0].w);
            o[4] = f2bf(wreg[it][1].x); o[5] = f2bf(wreg[it][1].y);
            o[6] = f2bf(wreg[it][1].z); o[7] = f2bf(wreg[it][1].w);
            *reinterpret_cast<ushort8*>(&Wl[buf][kr * 136 + c8]) = o;
        }
    };

    f32x4 acc[4] = {};
    float ss = 0.f;

    load_w(0);
    store_w(0);
    __syncthreads();

    for (int ch = 0; ch < 6; ++ch) {
        if (ch < 5) {
            load_w((ch + 1) << 7);
            store_w((ch + 1) & 1);
        }
        const int c0 = ch << 7;
        const unsigned short* Wb = Wl[ch & 1];

        #pragma unroll
        for (int s = 0; s < 4; ++s) {
            bf16x8 afrag;
            if (validA) {
                afrag = *reinterpret_cast<const bf16x8*>(gsrc + c0 + (s << 5));
            } else {
                #pragma unroll
                for (int j = 0; j < 8; ++j) ((unsigned short*)&afrag)[j] = 0;
            }
            #pragma unroll
            for (int j = 0; j < 8; ++j) {
                const float v = bf2f(((unsigned short*)&afrag)[j]);
                ss = fmaf(v, v, ss);
            }
            const int cl = (s << 5) + (lg << 3);
            #pragma unroll
            for (int rt = 0; rt < 4; ++rt) {
                bf16x8 bfrag = *reinterpret_cast<const bf16x8*>(&Wb[(rt*16 + lr)*136 + cl]);
                acc[rt] = __builtin_amdgcn_mfma_f32_16x16x32_bf16(afrag, bfrag, acc[rt], 0, 0, 0);
            }
        }

        __syncthreads();
    }

    // ---- token norm ----
    ss += __shfl_xor(ss, 16);
    ss += __shfl_xor(ss, 32);
    const float nrm = sqrtf(ss);
    const float inv = 1.0f / fmaxf(nrm, EPSF);

    // ---- logits + softmax over 64 regions ----
    float b_[4];
    #pragma unroll
    for (int rt = 0; rt < 4; ++rt) b_[rt] = conv_b[rt*16 + lr];

    float invT[4];
    #pragma unroll
    for (int reg = 0; reg < 4; ++reg) invT[reg] = __shfl(inv, (lg << 2) + reg);

    float lgt[4][4], mx[4];
    #pragma unroll
    for (int reg = 0; reg < 4; ++reg) {
        float m = -1e30f;
        #pragma unroll
        for (int rt = 0; rt < 4; ++rt) {
            lgt[rt][reg] = fmaf(acc[rt][reg], invT[reg], b_[rt]);
            m = fmaxf(m, lgt[rt][reg]);
        }
        mx[reg] = m;
    }
    #pragma unroll
    for (int msk = 1; msk < 16; msk <<= 1) {
        #pragma unroll
        for (int reg = 0; reg < 4; ++reg) mx[reg] = fmaxf(mx[reg], __shfl_xor(mx[reg], msk));
    }
    float ex[4][4], sm[4] = {0.f, 0.f, 0.f, 0.f};
    #pragma unroll
    for (int rt = 0; rt < 4; ++rt) {
        #pragma unroll
        for (int reg = 0; reg < 4; ++reg) {
            ex[rt][reg] = __expf(lgt[rt][reg] - mx[reg]);
            sm[reg] += ex[rt][reg];
        }
    }
    #pragma unroll
    for (int msk = 1; msk < 16; msk <<= 1) {
        #pragma unroll
        for (int reg = 0; reg < 4; ++reg) sm[reg] += __shfl_xor(sm[reg], msk);
    }

    float rsm[4];
    #pragma unroll
    for (int reg = 0; reg < 4; ++reg) {
        const bool vt = (t0w + (lg << 2) + reg) < TT;
        rsm[reg] = vt ? (1.0f / sm[reg]) : 0.f;
    }

    // ---- per-block partial asum ----
    float pa[4];
    #pragma unroll
    for (int rt = 0; rt < 4; ++rt) {
        pa[rt] = ex[rt][0]*rsm[0] + ex[rt][1]*rsm[1] + ex[rt][2]*rsm[2] + ex[rt][3]*rsm[3];
        pa[rt] += __shfl_xor(pa[rt], 16);
        pa[rt] += __shfl_xor(pa[rt], 32);
    }
    float* asum_lds = reinterpret_cast<float*>(&Wl[1][0]);
    if (lane < 16) {
        #pragma unroll
        for (int rt = 0; rt < 4; ++rt)
            asum_lds[(w << 6) + rt*16 + lane] = pa[rt];
    }

    // ---- a' transpose via LDS (aliased on Wl[0]) ----
    unsigned short* Abuf = &Wl[0][0] + (size_t)w * KR * 24;
    #pragma unroll
    for (int reg = 0; reg < 4; ++reg) {
        const int trow = (lg << 2) + reg;
        const float scale = invT[reg] * rsm[reg];
        #pragma unroll
        for (int rt = 0; rt < 4; ++rt)
            Abuf[(rt*16 + lr)*24 + trow] = f2bf(ex[rt][reg] * scale);
    }
    __syncthreads();

    if (tid < 64)
        ws_asum[(size_t)b * 64 + tid] =
            asum_lds[tid] + asum_lds[64 + tid] + asum_lds[128 + tid] + asum_lds[192 + tid];

    {
        ushort8 r0 = *reinterpret_cast<const ushort8*>(&Abuf[lane * 24]);
        ushort8 r1 = *reinterpret_cast<const ushort8*>(&Abuf[lane * 24 + 8]);
        unsigned short* dst = ws_a + ((size_t)n * KR + lane) * TP + t0w;
        *reinterpret_cast<ushort8*>(dst)     = r0;
        *reinterpret_cast<ushort8*>(dst + 8) = r1;
    }
}

// ---------------------------------------------------------------------------
// Kernel 2 (R13 + bf16 B-gathers from warm ws_g): GEMM2 (VLAD).
// ---------------------------------------------------------------------------
#define LOADA(d0,d1,d2,d3,t0_)                                                   \
    d0 = *reinterpret_cast<const bf16x8*>(abase +           (size_t)(t0_));      \
    d1 = *reinterpret_cast<const bf16x8*>(abase + 16*TP +   (size_t)(t0_));      \
    d2 = *reinterpret_cast<const bf16x8*>(abase + 32*TP +   (size_t)(t0_));      \
    d3 = *reinterpret_cast<const bf16x8*>(abase + 48*TP +   (size_t)(t0_));

#define LOADB(d,t0_) do {                                                        \
    const int tb2_ = (t0_) + (lg << 3);                                          \
    if ((t0_) + 32 <= TT) {                                                      \
        _Pragma("unroll")                                                        \
        for (int j_ = 0; j_ < 8; ++j_)                                           \
            ((unsigned short*)&(d))[j_] = gb[(size_t)(tb2_ + j_) * CCH];         \
    } else {                                                                     \
        _Pragma("unroll")                                                        \
        for (int j_ = 0; j_ < 8; ++j_)                                           \
            ((unsigned short*)&(d))[j_] =                                        \
                (tb2_ + j_ < TT) ? gb[(size_t)(tb2_ + j_) * CCH] : (unsigned short)0; \
    } } while (0)

__global__ __launch_bounds__(256, 4) void k_vlad(
    const unsigned short* __restrict__ ws_g,
    const unsigned short* __restrict__ ws_a,
    const float* __restrict__ ws_asum,
    const float* __restrict__ centroids,
    float* __restrict__ out)
{
    __shared__ float asum_s[64];

    const int tid  = threadIdx.x;
    const int lane = tid & 63;
    const int w    = tid >> 6;
    const int b    = (blockIdx.x & 7) * 96 + (blockIdx.x >> 3);
    const int n    = b / 12;
    const int c0   = (b - n * 12) << 6;
    const int lr   = lane & 15;
    const int lg   = lane >> 4;

    if (tid < 64) {
        float s = 0.f;
        #pragma unroll
        for (int bb = 0; bb < 10; ++bb)
            s += ws_asum[((size_t)n * 10 + bb) * 64 + tid];
        asum_s[tid] = s;
    }
    __syncthreads();

    const int c = c0 + (w << 4) + lr;
    const unsigned short* abase = ws_a + ((size_t)n * KR + lr) * TP + (lg << 3);
    const unsigned short* gb = ws_g + (size_t)n * TT * CCH + c;

    f32x4 acc0 = {}, acc1 = {}, acc2 = {}, acc3 = {};
    bf16x8 a0, a1, a2, a3, b0;
    bf16x8 p0, p1, p2, p3, q0;

    LOADA(a0, a1, a2, a3, 0)
    LOADB(b0, 0);

    int t0 = 0;
    while (true) {
        int tn = t0 + 32;
        if (tn < TT) { LOADA(p0, p1, p2, p3, tn) LOADB(q0, tn); }
        acc0 = __builtin_amdgcn_mfma_f32_16x16x32_bf16(a0, b0, acc0, 0, 0, 0);
        acc1 = __builtin_amdgcn_mfma_f32_16x16x32_bf16(a1, b0, acc1, 0, 0, 0);
        acc2 = __builtin_amdgcn_mfma_f32_16x16x32_bf16(a2, b0, acc2, 0, 0, 0);
        acc3 = __builtin_amdgcn_mfma_f32_16x16x32_bf16(a3, b0, acc3, 0, 0, 0);
        t0 = tn;
        if (t0 >= TT) break;

        tn = t0 + 32;
        if (tn < TT) { LOADA(a0, a1, a2, a3, tn) LOADB(b0, tn); }
        acc0 = __builtin_amdgcn_mfma_f32_16x16x32_bf16(p0, q0, acc0, 0, 0, 0);
        acc1 = __builtin_amdgcn_mfma_f32_16x16x32_bf16(p1, q0, acc1, 0, 0, 0);
        acc2 = __builtin_amdgcn_mfma_f32_16x16x32_bf16(p2, q0, acc2, 0, 0, 0);
        acc3 = __builtin_amdgcn_mfma_f32_16x16x32_bf16(p3, q0, acc3, 0, 0, 0);
        t0 = tn;
        if (t0 >= TT) break;
    }

    #pragma unroll
    for (int reg = 0; reg < 4; ++reg) {
        {
            const int kr = 0*16 + (lg << 2) + reg;
            out[((size_t)n * KR + kr) * CCH + c] =
                acc0[reg] - asum_s[kr] * centroids[(size_t)kr * CCH + c];
        }
        {
            const int kr = 1*16 + (lg << 2) + reg;
            out[((size_t)n * KR + kr) * CCH + c] =
                acc1[reg] - asum_s[kr] * centroids[(size_t)kr * CCH + c];
        }
        {
            const int kr = 2*16 + (lg << 2) + reg;
            out[((size_t)n * KR + kr) * CCH + c] =
                acc2[reg] - asum_s[kr] * centroids[(size_t)kr * CCH + c];
        }
        {
            const int kr = 3*16 + (lg << 2) + reg;
            out[((size_t)n * KR + kr) * CCH + c] =
                acc3[reg] - asum_s[kr] * centroids[(size_t)kr * CCH + c];
        }
    }
}

// ---------------------------------------------------------------------------
// Kernel 3: 4 rows per 256-thr block; global L2 norm of 64 unit rows = 8.
// ---------------------------------------------------------------------------
__global__ __launch_bounds__(256) void kc_norm_kernel(float* __restrict__ out)
{
    const int tid = threadIdx.x;
    const int sub = tid >> 6;
    const int l   = tid & 63;
    float4* p = reinterpret_cast<float4*>(out) + ((size_t)blockIdx.x * 4 + sub) * 192;
    float4 v0 = p[l];
    float4 v1 = p[l + 64];
    float4 v2 = p[l + 128];
    float ss = v0.x*v0.x + v0.y*v0.y + v0.z*v0.z + v0.w*v0.w
             + v1.x*v1.x + v1.y*v1.y + v1.z*v1.z + v1.w*v1.w
             + v2.x*v2.x + v2.y*v2.y + v2.z*v2.z + v2.w*v2.w;
    #pragma unroll
    for (int m = 1; m < 64; m <<= 1) ss += __shfl_xor(ss, m);
    const float sc = 0.125f / fmaxf(sqrtf(ss), EPSF);
    v0.x*=sc; v0.y*=sc; v0.z*=sc; v0.w*=sc;
    v1.x*=sc; v1.y*=sc; v1.z*=sc; v1.w*=sc;
    v2.x*=sc; v2.y*=sc; v2.z*=sc; v2.w*=sc;
    p[l] = v0;
    p[l + 64] = v1;
    p[l + 128] = v2;
}

extern "C" void kernel_launch(void* const* d_in, const int* in_sizes, int n_in,
                              void* d_out, int out_size, void* d_ws, size_t ws_size,
                              hipStream_t stream)
{
    const float* grids     = (const float*)d_in[0];
    const float* conv_w    = (const float*)d_in[1];
    const float* conv_b    = (const float*)d_in[2];
    const float* centroids = (const float*)d_in[3];
    float* out = (float*)d_out;

    // ws layout (bytes):
    //   ws_a    [0,          5,242,880)   64*64*640 bf16
    //   ws_asum [5,242,880,  5,406,720)   640*64 f32
    //   ws_g    [5,406,720, 62,128,128)   64*577*768 bf16 (56,721,408 B)
    unsigned short* ws_a    = (unsigned short*)d_ws;
    float*          ws_asum = (float*)((char*)d_ws + 5242880);
    unsigned short* ws_g    = (unsigned short*)((char*)d_ws + 5406720);

    hipLaunchKernelGGL(k_warm, dim3(2048), dim3(256), 0, stream, grids, ws_g);
    hipLaunchKernelGGL(k_logits, dim3(NB * 10), dim3(256), 0, stream,
                       ws_g, conv_w, conv_b, ws_a, ws_asum);
    hipLaunchKernelGGL(k_vlad, dim3(NB * 12), dim3(256), 0, stream,
                       ws_g, ws_a, ws_asum, centroids, out);
    hipLaunchKernelGGL(kc_norm_kernel, dim3(NB * KR / 4), dim3(256), 0, stream, out);
}